// Round 2
// baseline (111.797 us; speedup 1.0000x reference)
//
#include <hip/hip_runtime.h>

typedef float v2f __attribute__((ext_vector_type(2)));

#define SLOPE 0.2f

// v_pk_max_f32: leaky(v) == max(v, 0.2v) elementwise
static __device__ __forceinline__ v2f leaky2(v2f v) {
    return __builtin_elementwise_max(v, SLOPE * v);
}

// v_pk_fma_f32
static __device__ __forceinline__ v2f fma2(v2f a, v2f b, v2f c) {
    return __builtin_elementwise_fma(a, b, c);
}

static __device__ __forceinline__ float fast_tanh(float v) {
    // tanh(x) = 1 - 2/(exp(2x)+1); saturates correctly at +/-1.
    float e = __expf(2.0f * v);
    return 1.0f - 2.0f * __builtin_amdgcn_rcpf(e + 1.0f);
}

// lane <-> lane^1 exchange (pairs share a quad -> DPP-class shuffle)
static __device__ __forceinline__ v2f shfl_xor1(v2f v) {
    v2f r;
    r.x = __shfl_xor(v.x, 1, 64);
    r.y = __shfl_xor(v.y, 1, 64);
    return r;
}

// R7: position-split, 2 threads per sample.
// Evidence: dur_us 106.26 -> 106.22 (0.04%) across R1's structural change,
// and minigen fell out of rocprof top-5 (< 44 us warm; the R0 127.8 us row
// was the cold ord-0 dispatch). Timed region ~= 2x 44 us re-poison fills
// (268 MB @ 6.1 TB/s each) + ~18 us kernel slice. This round halves the
// kernel's serial-VALU chain and doubles wave count to attack that slice:
//  - lane pair (t, t^1) splits every conv by OUTPUT POSITION; weights stay
//    wave-uniform (SGPR). Channel-split would make weight loads divergent.
//  - halo columns exchanged via __shfl_xor(.,1); all edge clipping folded
//    into compile-time-indexed windows with zero ghosts (FMA w*0+s == s,
//    so accumulation is bit-identical to the unsplit kernel).
//  - 8192 single-wave blocks (was 4096): 8 waves/SIMD demanded.
// If dur_us stays at ~106.2 again, the metric is fill-floor-bound -> done.
__global__ __launch_bounds__(64, 6) void minigen_kernel(
    const float* __restrict__ x,
    const float* __restrict__ w1, const float* __restrict__ b1,
    const float* __restrict__ w2, const float* __restrict__ b2,
    const float* __restrict__ w3, const float* __restrict__ b3,
    const float* __restrict__ w4, const float* __restrict__ b4,
    float* __restrict__ out)
{
    __shared__ float4 lds[32 * 9];               // 4608 B, wave-private

    const int t = threadIdx.x;                   // 0..63 == lane
    const int s = t >> 1;                        // sample slot 0..31
    const int h = t & 1;                         // position half
    const int blockBase = blockIdx.x * 256;      // f4 units per 32 samples

    // ---- stage in: coalesced global -> LDS (256 f4 per wave) ----
    const float4* xin = (const float4*)x;
#pragma unroll
    for (int q = 0; q < 4; ++q) {
        int g = q * 64 + t;
        lds[(g >> 3) * 9 + (g & 7)] = xin[blockBase + g];
    }
    // no barrier: slab is wave-private; in-wave DS ops complete in order.

    // ---- input window xw[ic][0..8] = x[ic][8h-1 .. 8h+7] (ghost at 0) ----
    const float* slab = (const float*)lds;
    float xw[2][9];
#pragma unroll
    for (int c = 0; c < 2; ++c) {
        float4 a = lds[s*9 + c*4 + 2*h];         // x[c][8h .. 8h+3]
        float4 b = lds[s*9 + c*4 + 2*h + 1];     // x[c][8h+4 .. 8h+7]
        float gr = slab[s*36 + c*16 + 7];        // x[c][7] (pair-broadcast)
        xw[c][0] = h ? gr : 0.0f;                // x[c][-1] == pad 0 for h=0
        xw[c][1]=a.x; xw[c][2]=a.y; xw[c][3]=a.z; xw[c][4]=a.w;
        xw[c][5]=b.x; xw[c][6]=b.y; xw[c][7]=b.z; xw[c][8]=b.w;
    }

    // ---- conv1: this half computes e1 positions 4h..4h+3 (all 4 ch) ----
    // u_global = 2l-1+k = (8h-1) + (2*ll+k) -> window idx lu = 2*ll+k
    v2f e1p[2][4];                               // [ocpair][ll]
#pragma unroll
    for (int cp = 0; cp < 2; ++cp) {
#pragma unroll
        for (int ll = 0; ll < 4; ++ll) {
            v2f acc = { b1[2*cp], b1[2*cp+1] };
#pragma unroll
            for (int ic = 0; ic < 2; ++ic)
#pragma unroll
                for (int k = 0; k < 3; ++k) {
                    int lu = 2*ll + k;            // compile-time [0..8]
                    v2f w = { w1[((2*cp)*2 + ic)*3 + k],
                              w1[((2*cp+1)*2 + ic)*3 + k] };
                    float xv = xw[ic][lu];
                    acc = fma2(w, (v2f){xv, xv}, acc);
                }
            e1p[cp][ll] = leaky2(acc);
        }
    }

    // ---- conv2: bn positions 2h..2h+1 (all 8 ch as 4 oc-pairs) ----
    // u_global = 4h + (2*ll-1+k); window idx lw = 2*ll+k in [0..4];
    // lw==0 is e1[4h-1]: zero for h=0, partner's pos 3 for h=1.
    v2f e1g[2];
#pragma unroll
    for (int cp = 0; cp < 2; ++cp) {
        v2f r = shfl_xor1(e1p[cp][3]);
        e1g[cp] = h ? r : (v2f){0.0f, 0.0f};
    }

    v2f bnp[4][2];                               // [ocpair][ll]
#pragma unroll
    for (int cp = 0; cp < 4; ++cp) {
#pragma unroll
        for (int ll = 0; ll < 2; ++ll) {
            v2f acc = { b2[2*cp], b2[2*cp+1] };
#pragma unroll
            for (int ic = 0; ic < 4; ++ic)
#pragma unroll
                for (int k = 0; k < 3; ++k) {
                    int lw = 2*ll + k;            // compile-time [0..4]
                    int icp = ic >> 1;
                    v2f col = (lw == 0) ? e1g[icp] : e1p[icp][lw-1];
                    float ev = (ic & 1) ? col.y : col.x;
                    v2f w = { w2[((2*cp)*4 + ic)*3 + k],
                              w2[((2*cp+1)*4 + ic)*3 + k] };
                    acc = fma2(w, (v2f){ev, ev}, acc);
                }
            bnp[cp][ll] = leaky2(acc);
        }
    }

    // ---- up1 + conv3 + skip: positions 4h..4h+3 (all 4 ch) ----
    // u = 4h + c3, c3 = ll-1+k in [-1..5]; j = u>>1; window idx
    // jw = c3<0 ? 0 : (c3>>1)+1 in [0..3]. jw==0 is bn[2h-1] (h? partner
    // pos1 : 0); jw==3 is bn[2h+2] (h? 0 : partner pos2) -- the zero arms
    // also absorb the u<0 / u>=8 clips exactly.
    v2f bg0[4], bg3[4];
#pragma unroll
    for (int cp = 0; cp < 4; ++cp) {
        v2f r1 = shfl_xor1(bnp[cp][1]);
        v2f r0 = shfl_xor1(bnp[cp][0]);
        bg0[cp] = h ? r1 : (v2f){0.0f, 0.0f};
        bg3[cp] = h ? (v2f){0.0f, 0.0f} : r0;
    }

    v2f skp[2][4];                               // [ocpair][ll]
#pragma unroll
    for (int cp = 0; cp < 2; ++cp) {
#pragma unroll
        for (int ll = 0; ll < 4; ++ll) {
            v2f acc = { b3[2*cp], b3[2*cp+1] };
#pragma unroll
            for (int ic = 0; ic < 8; ++ic)
#pragma unroll
                for (int k = 0; k < 3; ++k) {
                    int c3 = ll - 1 + k;          // compile-time [-1..5]
                    int jw = (c3 < 0) ? 0 : (c3 >> 1) + 1;
                    int icp = ic >> 1;
                    v2f col = (jw == 0) ? bg0[icp]
                            : (jw == 3) ? bg3[icp]
                            : bnp[icp][jw-1];
                    float bv = (ic & 1) ? col.y : col.x;
                    v2f w = { w3[((2*cp)*8 + ic)*3 + k],
                              w3[((2*cp+1)*8 + ic)*3 + k] };
                    acc = fma2(w, (v2f){bv, bv}, acc);
                }
            skp[cp][ll] = leaky2(acc) + e1p[cp][ll];   // same positions
        }
    }

    // ---- up2 + conv4 + tanh: out positions 8h..8h+7 (both ch) ----
    // u = 8h + c4, c4 = ll-1+k in [-1..8]; jw = c4<0 ? 0 : (c4>>1)+1 in
    // [0..5]. jw==0 is skip[4h-1] (h? partner pos3 : 0); jw==5 is
    // skip[4h+4] (h? 0 : partner pos0), zero arms absorb u clips.
    v2f sg0[2], sg5[2];
#pragma unroll
    for (int cp = 0; cp < 2; ++cp) {
        v2f r3 = shfl_xor1(skp[cp][3]);
        v2f r0 = shfl_xor1(skp[cp][0]);
        sg0[cp] = h ? r3 : (v2f){0.0f, 0.0f};
        sg5[cp] = h ? (v2f){0.0f, 0.0f} : r0;
    }

    v2f op4[8];                                  // {ch0,ch1} x 8 positions
#pragma unroll
    for (int ll = 0; ll < 8; ++ll) {
        v2f acc = { b4[0], b4[1] };
#pragma unroll
        for (int ic = 0; ic < 4; ++ic)
#pragma unroll
            for (int k = 0; k < 3; ++k) {
                int c4 = ll - 1 + k;              // compile-time [-1..8]
                int jw = (c4 < 0) ? 0 : (c4 >> 1) + 1;
                int icp = ic >> 1;
                v2f col = (jw == 0) ? sg0[icp]
                        : (jw == 5) ? sg5[icp]
                        : skp[icp][jw-1];
                float sv = (ic & 1) ? col.y : col.x;
                v2f w = { w4[(0*4 + ic)*3 + k],
                          w4[(1*4 + ic)*3 + k] };
                acc = fma2(w, (v2f){sv, sv}, acc);
            }
        op4[ll] = (v2f){ fast_tanh(acc.x), fast_tanh(acc.y) };
    }

    // ---- own half back to LDS: ch0 f4 slots {2h,2h+1}, ch1 {4+2h,5+2h} ----
    // (input slab is dead; same-wave DS ops are in-order, no barrier)
#pragma unroll
    for (int m = 0; m < 2; ++m) {
        lds[s*9 + 2*h + m]     = make_float4(op4[4*m+0].x, op4[4*m+1].x,
                                             op4[4*m+2].x, op4[4*m+3].x);
        lds[s*9 + 4 + 2*h + m] = make_float4(op4[4*m+0].y, op4[4*m+1].y,
                                             op4[4*m+2].y, op4[4*m+3].y);
    }

    // ---- stage out: LDS -> coalesced global (1 KB per instruction) ----
    float4* outp = (float4*)out;
#pragma unroll
    for (int q = 0; q < 4; ++q) {
        int g = q * 64 + t;
        outp[blockBase + g] = lds[(g >> 3) * 9 + (g & 7)];
    }
}

extern "C" void kernel_launch(void* const* d_in, const int* in_sizes, int n_in,
                              void* d_out, int out_size, void* d_ws, size_t ws_size,
                              hipStream_t stream) {
    const float* x  = (const float*)d_in[0];
    const float* w1 = (const float*)d_in[1];
    const float* b1 = (const float*)d_in[2];
    const float* w2 = (const float*)d_in[3];
    const float* b2 = (const float*)d_in[4];
    const float* w3 = (const float*)d_in[5];
    const float* b3 = (const float*)d_in[6];
    const float* w4 = (const float*)d_in[7];
    const float* b4 = (const float*)d_in[8];
    float* out = (float*)d_out;

    int samples = in_sizes[0] / 32;      // 262144
    int grid = samples / 32;             // 8192 single-wave blocks, exact
    hipLaunchKernelGGL(minigen_kernel, dim3(grid), dim3(64), 0, stream,
                       x, w1, b1, w2, b2, w3, b3, w4, b4, out);
}

// Round 3
// 107.188 us; speedup vs baseline: 1.0430x; 1.0430x over previous
//
#include <hip/hip_runtime.h>

typedef float v2f __attribute__((ext_vector_type(2)));

#define SLOPE 0.2f

// v_pk_max_f32: leaky(v) == max(v, 0.2v) elementwise
static __device__ __forceinline__ v2f leaky2(v2f v) {
    return __builtin_elementwise_max(v, SLOPE * v);
}

// v_pk_fma_f32
static __device__ __forceinline__ v2f fma2(v2f a, v2f b, v2f c) {
    return __builtin_elementwise_fma(a, b, c);
}

static __device__ __forceinline__ float fast_tanh(float v) {
    // tanh(x) = 1 - 2/(exp(2x)+1); saturates correctly at +/-1.
    float e = __expf(2.0f * v);
    return 1.0f - 2.0f * __builtin_amdgcn_rcpf(e + 1.0f);
}

// R8: revert R7's position-split (regressed 106.2 -> 111.8: the 28
// ds_bpermute halo shuffles sat on the serial inter-conv dependency chain,
// costing more latency than the halved FMAs saved). Back to R6's 1-lane-per-
// sample single-wave blocks, with ONE targeted trim: the OUTPUT LDS
// round-trip is replaced by direct per-lane strided global_store_dwordx4
// (each lane owns 32 contiguous floats = 8 float4s). L2 write-combines the
// 128B-interleaved lanes across the 8 stores (same dirty lines), so HBM
// WRITE_SIZE is unchanged; we delete 16 DS ops + transpose packing + the
// final lgkmcnt bubble from each wave's tail. Input path untouched
// (coalesced 1KB/instr loads + LDS transpose — loads are latency-critical,
// stores are fire-and-forget).
__global__ __launch_bounds__(64, 6) void minigen_kernel(
    const float* __restrict__ x,
    const float* __restrict__ w1, const float* __restrict__ b1,
    const float* __restrict__ w2, const float* __restrict__ b2,
    const float* __restrict__ w3, const float* __restrict__ b3,
    const float* __restrict__ w4, const float* __restrict__ b4,
    float* __restrict__ out)
{
    __shared__ float4 lds[64 * 9];               // 9216 B, wave-private

    const int t = threadIdx.x;                   // 0..63 == lane
    const int blockBase = blockIdx.x * 512;      // f4 units per 64 samples

    // ---- stage in: coalesced global -> LDS (512 f4 per wave) ----
    const float4* xin = (const float4*)x;
#pragma unroll
    for (int q = 0; q < 8; ++q) {
        int g = q * 64 + t;
        lds[(g >> 3) * 9 + (g & 7)] = xin[blockBase + g];
    }
    // no __syncthreads(): slab touched only by this wave; in-wave DS order +
    // compiler lgkmcnt waits cover the RAW dependence.

    // ---- own sample: LDS -> registers, x[2][16] ----
    float xr[2][16];
#pragma unroll
    for (int m = 0; m < 8; ++m) {
        float4 v = lds[t * 9 + m];
        int c = m >> 2, base = (m & 3) * 4;
        xr[c][base+0] = v.x; xr[c][base+1] = v.y;
        xr[c][base+2] = v.z; xr[c][base+3] = v.w;
    }

    // ---- conv1: [2,16] -> [4,8], s2 p1, leaky; oc-pairs {2cp,2cp+1} ----
    v2f e1p[2][8];
#pragma unroll
    for (int cp = 0; cp < 2; ++cp) {
#pragma unroll
        for (int l = 0; l < 8; ++l) {
            v2f s = { b1[2*cp], b1[2*cp+1] };
#pragma unroll
            for (int ic = 0; ic < 2; ++ic)
#pragma unroll
                for (int k = 0; k < 3; ++k) {
                    int u = 2*l - 1 + k;          // [-1..15], compile-time
                    if (u >= 0) {
                        v2f w = { w1[((2*cp)*2 + ic)*3 + k],
                                  w1[((2*cp+1)*2 + ic)*3 + k] };
                        float xv = xr[ic][u];
                        s = fma2(w, (v2f){xv, xv}, s);
                    }
                }
            e1p[cp][l] = leaky2(s);
        }
    }

    // ---- conv2: [4,8] -> [8,4], s2 p1, leaky ----
    v2f bnp[4][4];
#pragma unroll
    for (int cp = 0; cp < 4; ++cp) {
#pragma unroll
        for (int l = 0; l < 4; ++l) {
            v2f s = { b2[2*cp], b2[2*cp+1] };
#pragma unroll
            for (int ic = 0; ic < 4; ++ic)
#pragma unroll
                for (int k = 0; k < 3; ++k) {
                    int u = 2*l - 1 + k;          // [-1..7]
                    if (u >= 0) {
                        float ev = (ic & 1) ? e1p[ic>>1][u].y
                                            : e1p[ic>>1][u].x;
                        v2f w = { w2[((2*cp)*4 + ic)*3 + k],
                                  w2[((2*cp+1)*4 + ic)*3 + k] };
                        s = fma2(w, (v2f){ev, ev}, s);
                    }
                }
            bnp[cp][l] = leaky2(s);
        }
    }

    // ---- up1(x2) + conv3: [8,8] -> [4,8], s1 p1, leaky, + skip e1 ----
    v2f skp[2][8];
#pragma unroll
    for (int cp = 0; cp < 2; ++cp) {
#pragma unroll
        for (int l = 0; l < 8; ++l) {
            v2f s = { b3[2*cp], b3[2*cp+1] };
#pragma unroll
            for (int ic = 0; ic < 8; ++ic)
#pragma unroll
                for (int k = 0; k < 3; ++k) {
                    int u = l - 1 + k;            // [-1..8]
                    if (u >= 0 && u < 8) {
                        int j = u >> 1;           // up1: nearest x2
                        float bv = (ic & 1) ? bnp[ic>>1][j].y
                                            : bnp[ic>>1][j].x;
                        v2f w = { w3[((2*cp)*8 + ic)*3 + k],
                                  w3[((2*cp+1)*8 + ic)*3 + k] };
                        s = fma2(w, (v2f){bv, bv}, s);
                    }
                }
            skp[cp][l] = leaky2(s) + e1p[cp][l];  // pair layouts match
        }
    }

    // ---- up2(x2) + conv4: [4,16] -> [2,16], s1 p1, tanh; oc-pair {0,1} ----
    v2f op4[16];
#pragma unroll
    for (int l = 0; l < 16; ++l) {
        v2f s = { b4[0], b4[1] };
#pragma unroll
        for (int ic = 0; ic < 4; ++ic)
#pragma unroll
            for (int k = 0; k < 3; ++k) {
                int u = l - 1 + k;                // [-1..16]
                if (u >= 0 && u < 16) {
                    int j = u >> 1;               // up2: nearest x2
                    float sv = (ic & 1) ? skp[ic>>1][j].y
                                        : skp[ic>>1][j].x;
                    v2f w = { w4[(0*4 + ic)*3 + k],
                              w4[(1*4 + ic)*3 + k] };
                    s = fma2(w, (v2f){sv, sv}, s);
                }
            }
        op4[l] = (v2f){ fast_tanh(s.x), fast_tanh(s.y) };
    }

    // ---- stage out: direct per-lane strided stores (no LDS round-trip) ----
    // Lane t owns out floats [(blockBase*4 + t*128) .. +127] = 8 float4s.
    // ch0[0..15] then ch1[0..15]; op4[l] = {ch0[l], ch1[l]}.
    float4* outp = (float4*)out + (size_t)blockBase + (size_t)t * 8;
#pragma unroll
    for (int m = 0; m < 4; ++m) {
        outp[m]     = make_float4(op4[4*m+0].x, op4[4*m+1].x,
                                  op4[4*m+2].x, op4[4*m+3].x);
        outp[4 + m] = make_float4(op4[4*m+0].y, op4[4*m+1].y,
                                  op4[4*m+2].y, op4[4*m+3].y);
    }
}

extern "C" void kernel_launch(void* const* d_in, const int* in_sizes, int n_in,
                              void* d_out, int out_size, void* d_ws, size_t ws_size,
                              hipStream_t stream) {
    const float* x  = (const float*)d_in[0];
    const float* w1 = (const float*)d_in[1];
    const float* b1 = (const float*)d_in[2];
    const float* w2 = (const float*)d_in[3];
    const float* b2 = (const float*)d_in[4];
    const float* w3 = (const float*)d_in[5];
    const float* b3 = (const float*)d_in[6];
    const float* w4 = (const float*)d_in[7];
    const float* b4 = (const float*)d_in[8];
    float* out = (float*)d_out;

    int samples = in_sizes[0] / 32;      // 262144
    int grid = samples / 64;             // 4096 single-wave blocks, exact
    hipLaunchKernelGGL(minigen_kernel, dim3(grid), dim3(64), 0, stream,
                       x, w1, b1, w2, b2, w3, b3, w4, b4, out);
}